// Round 10
// baseline (804.687 us; speedup 1.0000x reference)
//
#include <hip/hip_runtime.h>
#include <hip/hip_bf16.h>

// Problem constants
#define BB 64
#define SS 512
#define DD 128
#define NROW (BB * SS)          // 32768
#define SZ ((size_t)NROW * DD)  // 4,194,304 elems per [B,S,128] slice

#define LOG2E 1.4426950408889634f
#define QSCALE (0.125f * LOG2E)

typedef __attribute__((ext_vector_type(8))) short short8;
typedef __attribute__((ext_vector_type(4))) float f32x4;

// WB (converted-weight buffer) element offsets, all bf16:
#define WB_P1 0          // fc1W^T [128][320] (K=300 pad 320)
#define WB_P2 40960      // fc2W^T [128][64]  (K=35 pad 64)
#define WB_P3 49152      // fc3W^T [128][96]  (K=74 pad 96)
#define WB_QKVD 61440    // [4 op][6 u][128 n][128 k]  (op0=Wq prescaled by QSCALE)
#define WB_WIH 454656    // [6 rec][384 n][128 k]  (prescaled by log2e/2log2e)
#define WB_WHH 749568    // [6 rec][384 n][128 k]  (prescaled by log2e/2log2e)
#define WB_TOTAL 1044480

__device__ __forceinline__ float frcp_(float x) { return __builtin_amdgcn_rcpf(x); }
__device__ __forceinline__ float fexp2_(float x) { return __builtin_amdgcn_exp2f(x); }
__device__ __forceinline__ float b2f(unsigned short u) {
  union { unsigned int i; float f; } x; x.i = ((unsigned int)u) << 16; return x.f;
}
__device__ __forceinline__ unsigned short f2b(float f) {
  __hip_bfloat16 b = __float2bfloat16(f);
  return *reinterpret_cast<unsigned short*>(&b);
}
__device__ __forceinline__ unsigned short f2b_trunc(float f) {
  union { float f; unsigned int i; } x; x.f = f; return (unsigned short)(x.i >> 16);
}

// ---------------------------------------------------------------------------
// Weight prep.  Wq prescaled by QSCALE; GRU weights prescaled by log2e (r,z)
// / 2log2e (n).  gbihs = scale*(gbih + gbhh) for r,z gates (gbhh folded into
// the GX gemm bias); for the n gate gbihs = scale*gbih only (bhh_n must stay
// inside the r-product -> carried by the gru kernel's cbhn accumulator).
// ---------------------------------------------------------------------------
__global__ __launch_bounds__(256) void prep_kernel(
    const float* __restrict__ fc1W, const float* __restrict__ fc2W,
    const float* __restrict__ fc3W, const float* __restrict__ Wq,
    const float* __restrict__ Wk, const float* __restrict__ Wv,
    const float* __restrict__ Wd, const float* __restrict__ gWih,
    const float* __restrict__ gWhh, const float* __restrict__ gbih,
    const float* __restrict__ gbhh, const float* __restrict__ bq,
    unsigned short* __restrict__ WB, float* __restrict__ gbihs,
    float* __restrict__ bqs) {
  for (int idx = blockIdx.x * 256 + threadIdx.x; idx < WB_TOTAL;
       idx += gridDim.x * 256) {
    float v;
    if (idx < WB_P2) {
      int n = idx / 320, k = idx % 320;
      v = (k < 300) ? fc1W[k * 128 + n] : 0.f;
    } else if (idx < WB_P3) {
      int r = idx - WB_P2; int n = r >> 6, k = r & 63;
      v = (k < 35) ? fc2W[k * 128 + n] : 0.f;
    } else if (idx < WB_QKVD) {
      int r = idx - WB_P3; int n = r / 96, k = r % 96;
      v = (k < 74) ? fc3W[k * 128 + n] : 0.f;
    } else if (idx < WB_WIH) {
      int r = idx - WB_QKVD;
      int op = r / 98304; int r2 = r % 98304;
      int u = r2 >> 14; int r3 = r2 & 16383;
      int n = r3 >> 7, k = r3 & 127;
      const float* src = (op == 0) ? Wq : (op == 1) ? Wk : (op == 2) ? Wv : Wd;
      v = src[u * 16384 + k * 128 + n];
      if (op == 0) v *= QSCALE;
    } else if (idx < WB_WHH) {
      int r = idx - WB_WIH;
      int r3 = r % 49152;  // within rec: [384 n][128 k]
      int gate = (r3 >> 7) >> 7;
      v = gWih[r] * (gate < 2 ? LOG2E : 2.f * LOG2E);
    } else {
      int r = idx - WB_WHH;
      int r3 = r % 49152;
      int gate = (r3 >> 7) >> 7;
      v = gWhh[r] * (gate < 2 ? LOG2E : 2.f * LOG2E);
    }
    WB[idx] = f2b(v);
  }
  for (int idx = blockIdx.x * 256 + threadIdx.x; idx < 6 * 384;
       idx += gridDim.x * 256) {
    int gate = (idx % 384) >> 7;
    float v = gbih[idx] + (gate < 2 ? gbhh[idx] : 0.f);
    gbihs[idx] = v * (gate < 2 ? LOG2E : 2.f * LOG2E);
  }
  for (int idx = blockIdx.x * 256 + threadIdx.x; idx < 6 * 128;
       idx += gridDim.x * 256) {
    bqs[idx] = bq[idx] * QSCALE;
  }
}

// ---------------------------------------------------------------------------
// Batched MFMA GEMM: C[32768, ...] = A[32768,Ka] @ W^T + bias, per blockIdx.z.
// Row-major C with column stride cs (128 normal, 384 for the GX gemm).
// ---------------------------------------------------------------------------
struct GArg {
  const void* A; const unsigned short* W; const float* bias; void* C;
  int Ka, Kp, abf, cbf, cs;
};
struct GArgs { GArg g[18]; };

__global__ __launch_bounds__(256) void gemm_b(GArgs args) {
  const GArg ga = args.g[blockIdx.z];
  const int ny = blockIdx.y;
  __shared__ unsigned short As[128 * 40];
  __shared__ unsigned short Ws[128 * 40];
  const int t = threadIdx.x;
  const int w = t >> 6, lane = t & 63, q = lane >> 4, lm = lane & 15;
  const int wm = w >> 1, wn = w & 1;
  const int m0 = blockIdx.x * 128;
  const int row = t >> 1, cb = (t & 1) * 16;
  f32x4 acc[4][4];
#pragma unroll
  for (int i = 0; i < 4; ++i)
#pragma unroll
    for (int j = 0; j < 4; ++j) acc[i][j] = (f32x4){0.f, 0.f, 0.f, 0.f};

  for (int kt = 0; kt < ga.Kp; kt += 32) {
    if (ga.abf) {
      const unsigned short* Ag =
          (const unsigned short*)ga.A + (size_t)(m0 + row) * ga.Ka + kt + cb;
      short8 v0 = *reinterpret_cast<const short8*>(Ag);
      short8 v1 = *reinterpret_cast<const short8*>(Ag + 8);
      *reinterpret_cast<short8*>(&As[row * 40 + cb]) = v0;
      *reinterpret_cast<short8*>(&As[row * 40 + cb + 8]) = v1;
    } else {
      const float* Ag = (const float*)ga.A + (size_t)(m0 + row) * ga.Ka + kt + cb;
      unsigned short tmp[16];
#pragma unroll
      for (int j = 0; j < 16; ++j) {
        int k = kt + cb + j;
        tmp[j] = (k < ga.Ka) ? f2b(Ag[j]) : 0;
      }
      *reinterpret_cast<short8*>(&As[row * 40 + cb]) =
          *reinterpret_cast<short8*>(&tmp[0]);
      *reinterpret_cast<short8*>(&As[row * 40 + cb + 8]) =
          *reinterpret_cast<short8*>(&tmp[8]);
    }
    {
      const unsigned short* Wg =
          ga.W + (size_t)(ny * 128 + row) * ga.Kp + kt + cb;
      short8 v0 = *reinterpret_cast<const short8*>(Wg);
      short8 v1 = *reinterpret_cast<const short8*>(Wg + 8);
      *reinterpret_cast<short8*>(&Ws[row * 40 + cb]) = v0;
      *reinterpret_cast<short8*>(&Ws[row * 40 + cb + 8]) = v1;
    }
    __syncthreads();
    short8 af[4], bfv[4];
#pragma unroll
    for (int mi = 0; mi < 4; ++mi)
      af[mi] = *reinterpret_cast<const short8*>(
          &As[(wm * 64 + mi * 16 + lm) * 40 + q * 8]);
#pragma unroll
    for (int ni = 0; ni < 4; ++ni)
      bfv[ni] = *reinterpret_cast<const short8*>(
          &Ws[(wn * 64 + ni * 16 + lm) * 40 + q * 8]);
#pragma unroll
    for (int mi = 0; mi < 4; ++mi)
#pragma unroll
      for (int ni = 0; ni < 4; ++ni)
        acc[mi][ni] = __builtin_amdgcn_mfma_f32_16x16x32_bf16(
            af[mi], bfv[ni], acc[mi][ni], 0, 0, 0);
    __syncthreads();
  }
#pragma unroll
  for (int ni = 0; ni < 4; ++ni) {
    const int colg = ny * 128 + wn * 64 + ni * 16 + lm;
    const float bv = ga.bias[colg];
#pragma unroll
    for (int mi = 0; mi < 4; ++mi) {
      const int rg = m0 + wm * 64 + mi * 16 + q * 4;
#pragma unroll
      for (int r = 0; r < 4; ++r) {
        float v = acc[mi][ni][r] + bv;
        if (ga.cbf)
          ((unsigned short*)ga.C)[(size_t)(rg + r) * ga.cs + colg] = f2b(v);
        else
          ((float*)ga.C)[(size_t)(rg + r) * ga.cs + colg] = v;
      }
    }
  }
}

// ---------------------------------------------------------------------------
// V column sums: VS[z][b][128] = sum_s V_z[b][s][:]   (V bf16)
// ---------------------------------------------------------------------------
__global__ __launch_bounds__(128) void vsum_kernel(
    const unsigned short* __restrict__ QKV, float* __restrict__ VS) {
  int b = blockIdx.x, z = blockIdx.y, d = threadIdx.x;
  const unsigned short* p = QKV + (size_t)(z * 3 + 2) * SZ + (size_t)b * SS * DD + d;
  float s = 0.f;
  for (int k = 0; k < SS; ++k) s += b2f(p[(size_t)k * DD]);
  VS[(z * BB + b) * DD + d] = s;
}

// ---------------------------------------------------------------------------
// MFMA attention v2 (probs = 1 - softmax): ctx = Vsum - softmax(QK^T/8) @ V.
// grid = (2 q-halves, 128 = b*2+h, 3 units), block = 256 (4 waves).
// V staged once per k-tile; K/V B-frags register-resident, reused over 4
// q-tiles.  Persistent-zero C operand on the first S MFMA (no acc re-init).
// ---------------------------------------------------------------------------
__global__ __launch_bounds__(256) void attn2(
    const unsigned short* __restrict__ QKV, const float* __restrict__ VS,
    unsigned short* __restrict__ CTX) {
  __shared__ unsigned short Vt[64 * 72];       // [d][k ^ (d&56)]
  __shared__ unsigned short Pt[4][16 * 72];    // per-wave [q][k]
  const int t = threadIdx.x;
  const int w = t >> 6, lane = t & 63, quad = lane >> 4, lm = lane & 15;
  const int z = blockIdx.z;
  const int bh = blockIdx.y, b = bh >> 1, h = bh & 1;
  const int qbase = blockIdx.x * 256;

  const unsigned short* Qg = QKV + (size_t)(z * 3 + 0) * SZ;
  const unsigned short* Kg = QKV + (size_t)(z * 3 + 1) * SZ;
  const unsigned short* Vg = QKV + (size_t)(z * 3 + 2) * SZ;

  short8 aq[4][2];
#pragma unroll
  for (int qt = 0; qt < 4; ++qt)
#pragma unroll
    for (int c = 0; c < 2; ++c)
      aq[qt][c] = *reinterpret_cast<const short8*>(
          Qg + ((size_t)(b * SS + qbase + qt * 64 + w * 16 + lm)) * DD +
          h * 64 + c * 32 + quad * 8);

  const f32x4 czero = {0.f, 0.f, 0.f, 0.f};
  f32x4 o[4][4];  // [qt][dt]
#pragma unroll
  for (int i = 0; i < 4; ++i)
#pragma unroll
    for (int j = 0; j < 4; ++j) o[i][j] = czero;
  float suml[4][4];  // [qt][r]
#pragma unroll
  for (int i = 0; i < 4; ++i)
#pragma unroll
    for (int j = 0; j < 4; ++j) suml[i][j] = 0.f;

  const int vk = t >> 3, vd0 = (t & 7) * 8;

  for (int kt = 0; kt < 8; ++kt) {
    const int k0 = kt * 64;
    __syncthreads();  // prior Vt fully consumed (bv regs read)
#pragma unroll
    for (int i = 0; i < 2; ++i) {
      const int k = vk + i * 32;
      short8 vv = *reinterpret_cast<const short8*>(
          Vg + ((size_t)(b * SS + k0 + k)) * DD + h * 64 + vd0);
#pragma unroll
      for (int j = 0; j < 8; ++j) {
        const int d = vd0 + j;
        Vt[d * 72 + (k ^ (d & 56))] = (unsigned short)vv[j];
      }
    }
    __syncthreads();

    short8 bk[4][2];
#pragma unroll
    for (int nt = 0; nt < 4; ++nt)
#pragma unroll
      for (int c = 0; c < 2; ++c)
        bk[nt][c] = *reinterpret_cast<const short8*>(
            Kg + ((size_t)(b * SS + k0 + nt * 16 + lm)) * DD + h * 64 +
            c * 32 + quad * 8);
    short8 bvv[4][2];
#pragma unroll
    for (int dt = 0; dt < 4; ++dt) {
      const int d = dt * 16 + lm;
#pragma unroll
      for (int c = 0; c < 2; ++c)
        bvv[dt][c] = *reinterpret_cast<const short8*>(
            &Vt[d * 72 + ((c * 32 + quad * 8) ^ (d & 56))]);
    }

#pragma unroll
    for (int qt = 0; qt < 4; ++qt) {
      f32x4 sacc[4];
#pragma unroll
      for (int nt = 0; nt < 4; ++nt)
        sacc[nt] = __builtin_amdgcn_mfma_f32_16x16x32_bf16(
            aq[qt][0], bk[nt][0], czero, 0, 0, 0);
#pragma unroll
      for (int nt = 0; nt < 4; ++nt)
        sacc[nt] = __builtin_amdgcn_mfma_f32_16x16x32_bf16(
            aq[qt][1], bk[nt][1], sacc[nt], 0, 0, 0);
#pragma unroll
      for (int nt = 0; nt < 4; ++nt) {
#pragma unroll
        for (int r = 0; r < 4; ++r) {
          float p = fexp2_(sacc[nt][r]);
          suml[qt][r] += p;
          Pt[w][(quad * 4 + r) * 72 + nt * 16 + lm] = f2b_trunc(p);
        }
      }
#pragma unroll
      for (int c = 0; c < 2; ++c) {
        short8 ap = *reinterpret_cast<const short8*>(
            &Pt[w][lm * 72 + c * 32 + quad * 8]);
#pragma unroll
        for (int dt = 0; dt < 4; ++dt)
          o[qt][dt] = __builtin_amdgcn_mfma_f32_16x16x32_bf16(
              ap, bvv[dt][c], o[qt][dt], 0, 0, 0);
      }
    }
  }
#pragma unroll
  for (int qt = 0; qt < 4; ++qt)
#pragma unroll
    for (int r = 0; r < 4; ++r) {
#pragma unroll
      for (int m = 1; m < 16; m <<= 1)
        suml[qt][r] += __shfl_xor(suml[qt][r], m);
    }
  const float* vsp = VS + (size_t)(z * BB + b) * DD + h * 64;
#pragma unroll
  for (int qt = 0; qt < 4; ++qt)
#pragma unroll
    for (int dt = 0; dt < 4; ++dt) {
      const int col = dt * 16 + lm;
      const float vs = vsp[col];
#pragma unroll
      for (int r = 0; r < 4; ++r) {
        const int row = qbase + qt * 64 + w * 16 + quad * 4 + r;
        CTX[(size_t)z * SZ + ((size_t)(b * SS + row)) * DD + h * 64 + col] =
            f2b(vs - o[qt][dt][r] * frcp_(suml[qt][r]));
      }
    }
}

// ---------------------------------------------------------------------------
// Fused LN pair, 4 rows/block (1 wave per row).
// ---------------------------------------------------------------------------
__global__ __launch_bounds__(256) void ln_pair(
    const unsigned short* __restrict__ DOUT, const float* __restrict__ lng,
    const float* __restrict__ lnb, unsigned short* __restrict__ GRUIN) {
  const int g = blockIdx.y;
  const int row = blockIdx.x * 4 + (threadIdx.x >> 6);
  const int t = threadIdx.x & 63;
  const int u1t[3] = {1, 2, 0};
  const int u2t[3] = {3, 5, 4};
  float outA = 0.f, outB = 0.f;
#pragma unroll
  for (int half = 0; half < 2; ++half) {
    const int u = half == 0 ? u1t[g] : u2t[g];
    const unsigned short* x = DOUT + (size_t)u * SZ + (size_t)row * DD;
    float a = b2f(x[t]), c = b2f(x[t + 64]);
    float s = a + c, sq = a * a + c * c;
#pragma unroll
    for (int off = 32; off > 0; off >>= 1) {
      s += __shfl_down(s, off);
      sq += __shfl_down(sq, off);
    }
    s = __shfl(s, 0); sq = __shfl(sq, 0);
    float mean = s * (1.f / 128.f);
    float var = sq * (1.f / 128.f) - mean * mean;
    float rs = rsqrtf(var + 1e-5f);
    const float* gg = lng + u * 128;
    const float* bb = lnb + u * 128;
    outA += (a - mean) * rs * gg[t] + bb[t];
    outB += (c - mean) * rs * gg[t + 64] + bb[t + 64];
  }
  unsigned short* op = GRUIN + (size_t)g * SZ + (size_t)row * DD;
  op[t] = f2b(0.5f * outA);
  op[t + 64] = f2b(0.5f * outB);
}

// ---------------------------------------------------------------------------
// GRU v9: persistent C-operand accumulators (no per-step acc init; r,z gbhh
// folded into GX bias, bhn carried by cbhn), exec-masked ds_reads (only lanes
// lm%4==0 read the nonzero A rows; others hold persistent zero frags), lgkm-
// only barrier, coalesced GXR gate loads ring-prefetched 4 ahead.
// grid = (16 bg, 6 rec), block = 512 (8 waves).  batch <-> quad, A-row 4q.
// ---------------------------------------------------------------------------
#define AST 136

__global__ __launch_bounds__(512, 1) void gru7(
    const unsigned short* __restrict__ GXR, const unsigned short* __restrict__ WB,
    const float* __restrict__ gbhh, float* __restrict__ HS) {
  __shared__ unsigned short Abuf[2][16 * AST];
  const int rec = blockIdx.y, bg = blockIdx.x;
  const int dir = rec & 1;
  const int t = threadIdx.x;
  const int w = t >> 6, lane = t & 63, q = lane >> 4, lm = lane & 15;
  const int o = w * 16 + lm;
  const int b = bg * 4 + q;

  short8 Bh[3][4];
  const unsigned short* whh = WB + WB_WHH + (size_t)rec * 49152;
#pragma unroll
  for (int gate = 0; gate < 3; ++gate)
#pragma unroll
    for (int c = 0; c < 4; ++c)
      Bh[gate][c] = *reinterpret_cast<const short8*>(
          whh + (size_t)(gate * 128 + o) * 128 + c * 32 + q * 8);
  const float bhn = gbhh[rec * 384 + 256 + o] * (2.f * LOG2E);
  const f32x4 czero = {0.f, 0.f, 0.f, 0.f};
  const f32x4 cbhn = {bhn, 0.f, 0.f, 0.f};

  float h = 0.f, hsum = 0.f;
  for (int i = t; i < 2 * 16 * AST; i += 512)
    (&Abuf[0][0])[i] = 0;

  // gx: 3 ushort loads/step from GXR[rec][b*512 + tt][384] at cols g*128+o.
  const unsigned short* gx0 = GXR + (size_t)rec * 12582912 +
      ((size_t)b * 512 + (dir ? 511 : 0)) * 384 + o;
  const ptrdiff_t st = dir ? -384 : 384;

  unsigned short ring[4][3];
#pragma unroll
  for (int pp = 0; pp < 4; ++pp) {
    const unsigned short* gp = gx0 + (ptrdiff_t)pp * st;
#pragma unroll
    for (int j = 0; j < 3; ++j) ring[pp][j] = gp[j * 128];
  }

  // Persistent A fragments: lanes with lm%4!=0 map to always-zero A rows --
  // they keep these zero frags forever; only lm%4==0 lanes do ds_reads.
  const bool rdr = ((lm & 3) == 0);
  short8 ah0 = {0, 0, 0, 0, 0, 0, 0, 0};
  short8 ah1 = ah0, ah2 = ah0, ah3 = ah0;
  __syncthreads();

#pragma unroll 4
  for (int s = 0; s < SS; ++s) {
    const int p = s & 1, slot = s & 3;
    const float gxr = b2f(ring[slot][0]);
    const float gxz = b2f(ring[slot][1]);
    const float gxn = b2f(ring[slot][2]);
    // prefetch step s+4 (clamped)
    int sp = s + 4; if (sp > SS - 1) sp = SS - 1;
    const unsigned short* gp = gx0 + (ptrdiff_t)sp * st;
#pragma unroll
    for (int j = 0; j < 3; ++j) ring[slot][j] = gp[j * 128];

    if (rdr) {
      ah0 = *reinterpret_cast<const short8*>(&Abuf[p][lm * AST + 0 + q * 8]);
      ah1 = *reinterpret_cast<const short8*>(&Abuf[p][lm * AST + 32 + q * 8]);
      ah2 = *reinterpret_cast<const short8*>(&Abuf[p][lm * AST + 64 + q * 8]);
      ah3 = *reinterpret_cast<const short8*>(&Abuf[p][lm * AST + 96 + q * 8]);
    }
    f32x4 r0 = __builtin_amdgcn_mfma_f32_16x16x32_bf16(ah0, Bh[0][0], czero, 0, 0, 0);
    f32x4 r1 = __builtin_amdgcn_mfma_f32_16x16x32_bf16(ah2, Bh[0][2], czero, 0, 0, 0);
    f32x4 z0 = __builtin_amdgcn_mfma_f32_16x16x32_bf16(ah0, Bh[1][0], czero, 0, 0, 0);
    f32x4 z1 = __builtin_amdgcn_mfma_f32_16x16x32_bf16(ah2, Bh[1][2], czero, 0, 0, 0);
    f32x4 n0 = __builtin_amdgcn_mfma_f32_16x16x32_bf16(ah0, Bh[2][0], cbhn, 0, 0, 0);
    f32x4 n1 = __builtin_amdgcn_mfma_f32_16x16x32_bf16(ah2, Bh[2][2], czero, 0, 0, 0);
    r0 = __builtin_amdgcn_mfma_f32_16x16x32_bf16(ah1, Bh[0][1], r0, 0, 0, 0);
    r1 = __builtin_amdgcn_mfma_f32_16x16x32_bf16(ah3, Bh[0][3], r1, 0, 0, 0);
    z0 = __builtin_amdgcn_mfma_f32_16x16x32_bf16(ah1, Bh[1][1], z0, 0, 0, 0);
    z1 = __builtin_amdgcn_mfma_f32_16x16x32_bf16(ah3, Bh[1][3], z1, 0, 0, 0);
    n0 = __builtin_amdgcn_mfma_f32_16x16x32_bf16(ah1, Bh[2][1], n0, 0, 0, 0);
    n1 = __builtin_amdgcn_mfma_f32_16x16x32_bf16(ah3, Bh[2][3], n1, 0, 0, 0);

    float rr = frcp_(1.f + fexp2_(-(gxr + r0[0] + r1[0])));
    float zz = frcp_(1.f + fexp2_(-(gxz + z0[0] + z1[0])));
    float nn = 1.f - 2.f * frcp_(fexp2_(gxn + rr * (n0[0] + n1[0])) + 1.f);
    h = nn + zz * (h - nn);
    hsum += h;
    Abuf[p ^ 1][(q * 4) * AST + o] = f2b_trunc(h);
    asm volatile("s_waitcnt lgkmcnt(0)\n\ts_barrier" ::: "memory");
  }
  HS[((size_t)rec * BB + bg * 4 + q) * 128 + o] = hsum;
}

// ---------------------------------------------------------------------------
// Head: pooled -> Linear -> BN(eval) -> ReLU6 -> Linear.  grid=64, block=256.
// ---------------------------------------------------------------------------
__global__ __launch_bounds__(256) void head_kernel(
    const float* __restrict__ HS, const float* __restrict__ fW1,
    const float* __restrict__ fb1, const float* __restrict__ bng,
    const float* __restrict__ bnb, const float* __restrict__ fW2,
    const float* __restrict__ fb2, float* __restrict__ out) {
  __shared__ float pl[384];
  __shared__ float h1[256];
  int b = blockIdx.x, n = threadIdx.x;
  {
    int j = n;
    int seg = j >> 7, oo = j & 127;
    pl[j] = (HS[((size_t)seg * BB + b) * 128 + oo] +
             HS[((size_t)(seg + 3) * BB + b) * 128 + oo]) * (0.5f / 512.f);
  }
  if (n < 128) {
    int j = 256 + n;
    int seg = j >> 7, oo = j & 127;
    pl[j] = (HS[((size_t)seg * BB + b) * 128 + oo] +
             HS[((size_t)(seg + 3) * BB + b) * 128 + oo]) * (0.5f / 512.f);
  }
  __syncthreads();
  float acc = fb1[n];
  for (int k = 0; k < 384; ++k) acc += pl[k] * fW1[k * 256 + n];
  float hv = acc * rsqrtf(1.f + 1e-5f) * bng[n] + bnb[n];
  hv = fminf(fmaxf(hv, 0.f), 6.f);
  h1[n] = hv;
  __syncthreads();
  if (n < 8) {
    float a2 = fb2[n];
    for (int k = 0; k < 256; ++k) a2 += h1[k] * fW2[k * 8 + n];
    out[b * 8 + n] = a2;
  }
}

// ---------------------------------------------------------------------------
extern "C" void kernel_launch(void* const* d_in, const int* in_sizes, int n_in,
                              void* d_out, int out_size, void* d_ws,
                              size_t ws_size, hipStream_t stream) {
  (void)in_sizes; (void)n_in; (void)out_size; (void)ws_size;
  const float* text = (const float*)d_in[0];
  const float* vis  = (const float*)d_in[1];
  const float* aud  = (const float*)d_in[2];
  const float* fc1W = (const float*)d_in[3];
  const float* fc1b = (const float*)d_in[4];
  const float* fc2W = (const float*)d_in[5];
  const float* fc2b = (const float*)d_in[6];
  const float* fc3W = (const float*)d_in[7];
  const float* fc3b = (const float*)d_in[8];
  const float* Wq = (const float*)d_in[9];
  const float* bq = (const float*)d_in[10];
  const float* Wk = (const float*)d_in[11];
  const float* bk = (const float*)d_in[12];
  const float* Wv = (const float*)d_in[13];
  const float* bv = (const float*)d_in[14];
  const float* Wd = (const float*)d_in[15];
  const float* bd = (const float*)d_in[16];
  const float* lng = (const float*)d_in[17];
  const float* lnb = (const float*)d_in[18];
  const float* gWih = (const float*)d_in[19];
  const float* gWhh = (const float*)d_in[20];
  const float* gbih = (const float*)d_in[21];
  const float* gbhh = (const float*)d_in[22];
  const float* fW1 = (const float*)d_in[23];
  const float* fb1 = (const float*)d_in[24];
  const float* bng = (const float*)d_in[25];
  const float* bnb = (const float*)d_in[26];
  const float* fW2 = (const float*)d_in[27];
  const float* fb2 = (const float*)d_in[28];
  float* out = (float*)d_out;

  unsigned short* WSB = (unsigned short*)d_ws;
  unsigned short* T   = WSB;
  unsigned short* Vv  = WSB + SZ;
  unsigned short* Aa  = WSB + 2 * SZ;
  unsigned short* QKV = WSB + 3 * SZ;
  unsigned short* CTX = WSB + 12 * SZ;
  unsigned short* DOUT = WSB;
  unsigned short* GXR = WSB;              // slices 0..17 ([6][32768][384])
  unsigned short* GRUIN = WSB + 18 * SZ;  // slices 18..20
  unsigned short* WB  = WSB + 21 * SZ;
  float* VS = (float*)(WSB + 21 * SZ + 1048576);
  float* HS = VS + 6 * 64 * 128;
  float* gbihs = HS + 6 * 64 * 128;       // 2304 floats
  float* bqs = gbihs + 6 * 384;           // 768 floats

  prep_kernel<<<dim3(1024), dim3(256), 0, stream>>>(
      fc1W, fc2W, fc3W, Wq, Wk, Wv, Wd, gWih, gWhh, gbih, gbhh, bq, WB,
      gbihs, bqs);

  {
    GArgs ga{};
    ga.g[0] = {text, WB + WB_P1, fc1b, T, 300, 320, 0, 1, 128};
    ga.g[1] = {vis,  WB + WB_P2, fc2b, Vv, 35, 64, 0, 1, 128};
    ga.g[2] = {aud,  WB + WB_P3, fc3b, Aa, 74, 96, 0, 1, 128};
    gemm_b<<<dim3(256, 1, 3), dim3(256), 0, stream>>>(ga);
  }

  const int qsel[6] = {0, 2, 0, 1, 1, 2};
  const int ksel[6] = {2, 0, 1, 0, 2, 1};
  unsigned short* proj[3] = {T, Vv, Aa};

  for (int phase = 0; phase < 2; ++phase) {
    GArgs ga{};
    for (int ul = 0; ul < 3; ++ul) {
      int u = phase * 3 + ul;
      for (int op = 0; op < 3; ++op) {
        int z = ul * 3 + op;
        const float* bias = (op == 0) ? (bqs + u * 128)
                          : (op == 1) ? (bk + u * 128) : (bv + u * 128);
        ga.g[z] = {proj[op == 0 ? qsel[u] : ksel[u]],
                   WB + WB_QKVD + op * 98304 + u * 16384, bias,
                   QKV + (size_t)z * SZ, 128, 128, 1, 1, 128};
      }
    }
    gemm_b<<<dim3(256, 1, 9), dim3(256), 0, stream>>>(ga);
    vsum_kernel<<<dim3(BB, 3), dim3(128), 0, stream>>>(QKV, VS + phase * 3 * BB * DD);
    attn2<<<dim3(2, 128, 3), dim3(256), 0, stream>>>(
        QKV, VS + phase * 3 * BB * DD, CTX + (size_t)phase * 3 * SZ);
  }

  {
    GArgs ga{};
    for (int u = 0; u < 6; ++u)
      ga.g[u] = {CTX + (size_t)u * SZ, WB + WB_QKVD + 3 * 98304 + u * 16384,
                 bd + u * 128, DOUT + (size_t)u * SZ, 128, 128, 1, 1, 128};
    gemm_b<<<dim3(256, 1, 6), dim3(256), 0, stream>>>(ga);
  }

  ln_pair<<<dim3(NROW / 4, 3), dim3(256), 0, stream>>>(DOUT, lng, lnb, GRUIN);

  // gx = GRUIN[g] @ Wih[rec]^T + gbihs[rec] -> row-major GXR (coalesced)
  {
    GArgs ga{};
    for (int r6 = 0; r6 < 6; ++r6) {
      int g = r6 >> 1;
      ga.g[r6] = {GRUIN + (size_t)g * SZ, WB + WB_WIH + r6 * 49152,
                  gbihs + r6 * 384, GXR + (size_t)r6 * 12582912,
                  128, 128, 1, 1, 384};
    }
    gemm_b<<<dim3(256, 3, 6), dim3(256), 0, stream>>>(ga);
  }

  gru7<<<dim3(16, 6), dim3(512), 0, stream>>>(GXR, WB, gbhh, HS);
  head_kernel<<<dim3(BB), dim3(256), 0, stream>>>(HS, fW1, fb1, bng, bnb, fW2, fb2, out);
}

// Round 11
// 757.047 us; speedup vs baseline: 1.0629x; 1.0629x over previous
//
#include <hip/hip_runtime.h>
#include <hip/hip_bf16.h>

// Problem constants
#define BB 64
#define SS 512
#define DD 128
#define NROW (BB * SS)          // 32768
#define SZ ((size_t)NROW * DD)  // 4,194,304 elems per [B,S,128] slice

#define LOG2E 1.4426950408889634f
#define QSCALE (0.125f * LOG2E)

typedef __attribute__((ext_vector_type(8))) short short8;
typedef __attribute__((ext_vector_type(4))) float f32x4;

// WB (converted-weight buffer) element offsets, all bf16:
#define WB_P1 0          // fc1W^T [128][320] (K=300 pad 320)
#define WB_P2 40960      // fc2W^T [128][64]  (K=35 pad 64)
#define WB_P3 49152      // fc3W^T [128][96]  (K=74 pad 96)
#define WB_QKVD 61440    // [4 op][6 u][128 n][128 k]  (op0=Wq prescaled by QSCALE)
#define WB_WIH 454656    // [6 rec][384 n][128 k]  (prescaled by log2e/2log2e)
#define WB_WHH 749568    // [6 rec][384 n][128 k]  (prescaled by log2e/2log2e)
#define WB_TOTAL 1044480

__device__ __forceinline__ float frcp_(float x) { return __builtin_amdgcn_rcpf(x); }
__device__ __forceinline__ float fexp2_(float x) { return __builtin_amdgcn_exp2f(x); }
__device__ __forceinline__ float b2f(unsigned short u) {
  union { unsigned int i; float f; } x; x.i = ((unsigned int)u) << 16; return x.f;
}
__device__ __forceinline__ unsigned short f2b(float f) {
  __hip_bfloat16 b = __float2bfloat16(f);
  return *reinterpret_cast<unsigned short*>(&b);
}
__device__ __forceinline__ unsigned short f2b_trunc(float f) {
  union { float f; unsigned int i; } x; x.f = f; return (unsigned short)(x.i >> 16);
}

// ---------------------------------------------------------------------------
// Weight prep.  Wq prescaled by QSCALE; GRU weights prescaled by log2e (r,z)
// / 2log2e (n).  gbihs = scale*(gbih + gbhh) for r,z gates (gbhh folded into
// the GX gemm bias); for the n gate gbihs = scale*gbih only (bhh_n must stay
// inside the r-product -> carried by the gru kernel's cbhn accumulator).
// ---------------------------------------------------------------------------
__global__ __launch_bounds__(256) void prep_kernel(
    const float* __restrict__ fc1W, const float* __restrict__ fc2W,
    const float* __restrict__ fc3W, const float* __restrict__ Wq,
    const float* __restrict__ Wk, const float* __restrict__ Wv,
    const float* __restrict__ Wd, const float* __restrict__ gWih,
    const float* __restrict__ gWhh, const float* __restrict__ gbih,
    const float* __restrict__ gbhh, const float* __restrict__ bq,
    unsigned short* __restrict__ WB, float* __restrict__ gbihs,
    float* __restrict__ bqs) {
  for (int idx = blockIdx.x * 256 + threadIdx.x; idx < WB_TOTAL;
       idx += gridDim.x * 256) {
    float v;
    if (idx < WB_P2) {
      int n = idx / 320, k = idx % 320;
      v = (k < 300) ? fc1W[k * 128 + n] : 0.f;
    } else if (idx < WB_P3) {
      int r = idx - WB_P2; int n = r >> 6, k = r & 63;
      v = (k < 35) ? fc2W[k * 128 + n] : 0.f;
    } else if (idx < WB_QKVD) {
      int r = idx - WB_P3; int n = r / 96, k = r % 96;
      v = (k < 74) ? fc3W[k * 128 + n] : 0.f;
    } else if (idx < WB_WIH) {
      int r = idx - WB_QKVD;
      int op = r / 98304; int r2 = r % 98304;
      int u = r2 >> 14; int r3 = r2 & 16383;
      int n = r3 >> 7, k = r3 & 127;
      const float* src = (op == 0) ? Wq : (op == 1) ? Wk : (op == 2) ? Wv : Wd;
      v = src[u * 16384 + k * 128 + n];
      if (op == 0) v *= QSCALE;
    } else if (idx < WB_WHH) {
      int r = idx - WB_WIH;
      int r3 = r % 49152;  // within rec: [384 n][128 k]
      int gate = (r3 >> 7) >> 7;
      v = gWih[r] * (gate < 2 ? LOG2E : 2.f * LOG2E);
    } else {
      int r = idx - WB_WHH;
      int r3 = r % 49152;
      int gate = (r3 >> 7) >> 7;
      v = gWhh[r] * (gate < 2 ? LOG2E : 2.f * LOG2E);
    }
    WB[idx] = f2b(v);
  }
  for (int idx = blockIdx.x * 256 + threadIdx.x; idx < 6 * 384;
       idx += gridDim.x * 256) {
    int gate = (idx % 384) >> 7;
    float v = gbih[idx] + (gate < 2 ? gbhh[idx] : 0.f);
    gbihs[idx] = v * (gate < 2 ? LOG2E : 2.f * LOG2E);
  }
  for (int idx = blockIdx.x * 256 + threadIdx.x; idx < 6 * 128;
       idx += gridDim.x * 256) {
    bqs[idx] = bq[idx] * QSCALE;
  }
}

// ---------------------------------------------------------------------------
// Batched MFMA GEMM: C[32768, ...] = A[32768,Ka] @ W^T + bias, per blockIdx.z.
// Row-major C with column stride cs.  If vsum != null (V-projection slices),
// per-column partial sums (bias included) are atomically accumulated into
// vsum[b*128 + col] -- fuses the old vsum_kernel into the epilogue.
// ---------------------------------------------------------------------------
struct GArg {
  const void* A; const unsigned short* W; const float* bias; void* C;
  int Ka, Kp, abf, cbf, cs; float* vsum;
};
struct GArgs { GArg g[18]; };

__global__ __launch_bounds__(256) void gemm_b(GArgs args) {
  const GArg ga = args.g[blockIdx.z];
  const int ny = blockIdx.y;
  __shared__ unsigned short As[128 * 40];
  __shared__ unsigned short Ws[128 * 40];
  const int t = threadIdx.x;
  const int w = t >> 6, lane = t & 63, q = lane >> 4, lm = lane & 15;
  const int wm = w >> 1, wn = w & 1;
  const int m0 = blockIdx.x * 128;
  const int row = t >> 1, cb = (t & 1) * 16;
  f32x4 acc[4][4];
#pragma unroll
  for (int i = 0; i < 4; ++i)
#pragma unroll
    for (int j = 0; j < 4; ++j) acc[i][j] = (f32x4){0.f, 0.f, 0.f, 0.f};

  for (int kt = 0; kt < ga.Kp; kt += 32) {
    if (ga.abf) {
      const unsigned short* Ag =
          (const unsigned short*)ga.A + (size_t)(m0 + row) * ga.Ka + kt + cb;
      short8 v0 = *reinterpret_cast<const short8*>(Ag);
      short8 v1 = *reinterpret_cast<const short8*>(Ag + 8);
      *reinterpret_cast<short8*>(&As[row * 40 + cb]) = v0;
      *reinterpret_cast<short8*>(&As[row * 40 + cb + 8]) = v1;
    } else {
      const float* Ag = (const float*)ga.A + (size_t)(m0 + row) * ga.Ka + kt + cb;
      unsigned short tmp[16];
#pragma unroll
      for (int j = 0; j < 16; ++j) {
        int k = kt + cb + j;
        tmp[j] = (k < ga.Ka) ? f2b(Ag[j]) : 0;
      }
      *reinterpret_cast<short8*>(&As[row * 40 + cb]) =
          *reinterpret_cast<short8*>(&tmp[0]);
      *reinterpret_cast<short8*>(&As[row * 40 + cb + 8]) =
          *reinterpret_cast<short8*>(&tmp[8]);
    }
    {
      const unsigned short* Wg =
          ga.W + (size_t)(ny * 128 + row) * ga.Kp + kt + cb;
      short8 v0 = *reinterpret_cast<const short8*>(Wg);
      short8 v1 = *reinterpret_cast<const short8*>(Wg + 8);
      *reinterpret_cast<short8*>(&Ws[row * 40 + cb]) = v0;
      *reinterpret_cast<short8*>(&Ws[row * 40 + cb + 8]) = v1;
    }
    __syncthreads();
    short8 af[4], bfv[4];
#pragma unroll
    for (int mi = 0; mi < 4; ++mi)
      af[mi] = *reinterpret_cast<const short8*>(
          &As[(wm * 64 + mi * 16 + lm) * 40 + q * 8]);
#pragma unroll
    for (int ni = 0; ni < 4; ++ni)
      bfv[ni] = *reinterpret_cast<const short8*>(
          &Ws[(wn * 64 + ni * 16 + lm) * 40 + q * 8]);
#pragma unroll
    for (int mi = 0; mi < 4; ++mi)
#pragma unroll
      for (int ni = 0; ni < 4; ++ni)
        acc[mi][ni] = __builtin_amdgcn_mfma_f32_16x16x32_bf16(
            af[mi], bfv[ni], acc[mi][ni], 0, 0, 0);
    __syncthreads();
  }
#pragma unroll
  for (int ni = 0; ni < 4; ++ni) {
    const int colg = ny * 128 + wn * 64 + ni * 16 + lm;
    const float bv = ga.bias[colg];
#pragma unroll
    for (int mi = 0; mi < 4; ++mi) {
      const int rg = m0 + wm * 64 + mi * 16 + q * 4;
#pragma unroll
      for (int r = 0; r < 4; ++r) {
        float v = acc[mi][ni][r] + bv;
        if (ga.cbf)
          ((unsigned short*)ga.C)[(size_t)(rg + r) * ga.cs + colg] = f2b(v);
        else
          ((float*)ga.C)[(size_t)(rg + r) * ga.cs + colg] = v;
      }
    }
  }
  if (ga.vsum) {
    // all 128 block-rows are within batch b = m0>>9 (512-row batches)
    float* vp = ga.vsum + (size_t)(m0 >> 9) * 128;
#pragma unroll
    for (int ni = 0; ni < 4; ++ni) {
      const int colg = wn * 64 + ni * 16 + lm;
      float s = 16.f * ga.bias[colg];
#pragma unroll
      for (int mi = 0; mi < 4; ++mi)
#pragma unroll
        for (int r = 0; r < 4; ++r) s += acc[mi][ni][r];
      atomicAdd(&vp[colg], s);
    }
  }
}

// ---------------------------------------------------------------------------
// MFMA attention v2 (probs = 1 - softmax): ctx = Vsum - softmax(QK^T/8) @ V.
// grid = (2 q-halves, 128 = b*2+h, 3 units), block = 256 (4 waves).
// V staged once per k-tile; K/V B-frags register-resident, reused over 4
// q-tiles.  Persistent-zero C operand on the first S MFMA (no acc re-init).
// ---------------------------------------------------------------------------
__global__ __launch_bounds__(256) void attn2(
    const unsigned short* __restrict__ QKV, const float* __restrict__ VS,
    unsigned short* __restrict__ CTX) {
  __shared__ unsigned short Vt[64 * 72];       // [d][k ^ (d&56)]
  __shared__ unsigned short Pt[4][16 * 72];    // per-wave [q][k]
  const int t = threadIdx.x;
  const int w = t >> 6, lane = t & 63, quad = lane >> 4, lm = lane & 15;
  const int z = blockIdx.z;
  const int bh = blockIdx.y, b = bh >> 1, h = bh & 1;
  const int qbase = blockIdx.x * 256;

  const unsigned short* Qg = QKV + (size_t)(z * 3 + 0) * SZ;
  const unsigned short* Kg = QKV + (size_t)(z * 3 + 1) * SZ;
  const unsigned short* Vg = QKV + (size_t)(z * 3 + 2) * SZ;

  short8 aq[4][2];
#pragma unroll
  for (int qt = 0; qt < 4; ++qt)
#pragma unroll
    for (int c = 0; c < 2; ++c)
      aq[qt][c] = *reinterpret_cast<const short8*>(
          Qg + ((size_t)(b * SS + qbase + qt * 64 + w * 16 + lm)) * DD +
          h * 64 + c * 32 + quad * 8);

  const f32x4 czero = {0.f, 0.f, 0.f, 0.f};
  f32x4 o[4][4];  // [qt][dt]
#pragma unroll
  for (int i = 0; i < 4; ++i)
#pragma unroll
    for (int j = 0; j < 4; ++j) o[i][j] = czero;
  float suml[4][4];  // [qt][r]
#pragma unroll
  for (int i = 0; i < 4; ++i)
#pragma unroll
    for (int j = 0; j < 4; ++j) suml[i][j] = 0.f;

  const int vk = t >> 3, vd0 = (t & 7) * 8;

  for (int kt = 0; kt < 8; ++kt) {
    const int k0 = kt * 64;
    __syncthreads();  // prior Vt fully consumed (bv regs read)
#pragma unroll
    for (int i = 0; i < 2; ++i) {
      const int k = vk + i * 32;
      short8 vv = *reinterpret_cast<const short8*>(
          Vg + ((size_t)(b * SS + k0 + k)) * DD + h * 64 + vd0);
#pragma unroll
      for (int j = 0; j < 8; ++j) {
        const int d = vd0 + j;
        Vt[d * 72 + (k ^ (d & 56))] = (unsigned short)vv[j];
      }
    }
    __syncthreads();

    short8 bk[4][2];
#pragma unroll
    for (int nt = 0; nt < 4; ++nt)
#pragma unroll
      for (int c = 0; c < 2; ++c)
        bk[nt][c] = *reinterpret_cast<const short8*>(
            Kg + ((size_t)(b * SS + k0 + nt * 16 + lm)) * DD + h * 64 +
            c * 32 + quad * 8);
    short8 bvv[4][2];
#pragma unroll
    for (int dt = 0; dt < 4; ++dt) {
      const int d = dt * 16 + lm;
#pragma unroll
      for (int c = 0; c < 2; ++c)
        bvv[dt][c] = *reinterpret_cast<const short8*>(
            &Vt[d * 72 + ((c * 32 + quad * 8) ^ (d & 56))]);
    }

#pragma unroll
    for (int qt = 0; qt < 4; ++qt) {
      f32x4 sacc[4];
#pragma unroll
      for (int nt = 0; nt < 4; ++nt)
        sacc[nt] = __builtin_amdgcn_mfma_f32_16x16x32_bf16(
            aq[qt][0], bk[nt][0], czero, 0, 0, 0);
#pragma unroll
      for (int nt = 0; nt < 4; ++nt)
        sacc[nt] = __builtin_amdgcn_mfma_f32_16x16x32_bf16(
            aq[qt][1], bk[nt][1], sacc[nt], 0, 0, 0);
#pragma unroll
      for (int nt = 0; nt < 4; ++nt) {
#pragma unroll
        for (int r = 0; r < 4; ++r) {
          float p = fexp2_(sacc[nt][r]);
          suml[qt][r] += p;
          Pt[w][(quad * 4 + r) * 72 + nt * 16 + lm] = f2b_trunc(p);
        }
      }
#pragma unroll
      for (int c = 0; c < 2; ++c) {
        short8 ap = *reinterpret_cast<const short8*>(
            &Pt[w][lm * 72 + c * 32 + quad * 8]);
#pragma unroll
        for (int dt = 0; dt < 4; ++dt)
          o[qt][dt] = __builtin_amdgcn_mfma_f32_16x16x32_bf16(
              ap, bvv[dt][c], o[qt][dt], 0, 0, 0);
      }
    }
  }
#pragma unroll
  for (int qt = 0; qt < 4; ++qt)
#pragma unroll
    for (int r = 0; r < 4; ++r) {
#pragma unroll
      for (int m = 1; m < 16; m <<= 1)
        suml[qt][r] += __shfl_xor(suml[qt][r], m);
    }
  const float* vsp = VS + (size_t)(z * BB + b) * DD + h * 64;
#pragma unroll
  for (int qt = 0; qt < 4; ++qt)
#pragma unroll
    for (int dt = 0; dt < 4; ++dt) {
      const int col = dt * 16 + lm;
      const float vs = vsp[col];
#pragma unroll
      for (int r = 0; r < 4; ++r) {
        const int row = qbase + qt * 64 + w * 16 + quad * 4 + r;
        CTX[(size_t)z * SZ + ((size_t)(b * SS + row)) * DD + h * 64 + col] =
            f2b(vs - o[qt][dt][r] * frcp_(suml[qt][r]));
      }
    }
}

// ---------------------------------------------------------------------------
// Fused LN pair, 4 rows/block (1 wave per row).
// ---------------------------------------------------------------------------
__global__ __launch_bounds__(256) void ln_pair(
    const unsigned short* __restrict__ DOUT, const float* __restrict__ lng,
    const float* __restrict__ lnb, unsigned short* __restrict__ GRUIN) {
  const int g = blockIdx.y;
  const int row = blockIdx.x * 4 + (threadIdx.x >> 6);
  const int t = threadIdx.x & 63;
  const int u1t[3] = {1, 2, 0};
  const int u2t[3] = {3, 5, 4};
  float outA = 0.f, outB = 0.f;
#pragma unroll
  for (int half = 0; half < 2; ++half) {
    const int u = half == 0 ? u1t[g] : u2t[g];
    const unsigned short* x = DOUT + (size_t)u * SZ + (size_t)row * DD;
    float a = b2f(x[t]), c = b2f(x[t + 64]);
    float s = a + c, sq = a * a + c * c;
#pragma unroll
    for (int off = 32; off > 0; off >>= 1) {
      s += __shfl_down(s, off);
      sq += __shfl_down(sq, off);
    }
    s = __shfl(s, 0); sq = __shfl(sq, 0);
    float mean = s * (1.f / 128.f);
    float var = sq * (1.f / 128.f) - mean * mean;
    float rs = rsqrtf(var + 1e-5f);
    const float* gg = lng + u * 128;
    const float* bb = lnb + u * 128;
    outA += (a - mean) * rs * gg[t] + bb[t];
    outB += (c - mean) * rs * gg[t + 64] + bb[t + 64];
  }
  unsigned short* op = GRUIN + (size_t)g * SZ + (size_t)row * DD;
  op[t] = f2b(0.5f * outA);
  op[t + 64] = f2b(0.5f * outB);
}

// ---------------------------------------------------------------------------
// GRU v10: unconditional ds_reads restored (round-10 exec-mask branch was a
// regression: conflicts were off the critical path, branch cost was real).
// Keeps persistent czero/cbhn C-operands + folded biases; lgkm-only barrier;
// coalesced GXR gate loads with pointer-bump ring prefetch (4 ahead).
// grid = (16 bg, 6 rec), block = 512 (8 waves).  batch <-> quad, A-row 4q.
// ---------------------------------------------------------------------------
#define AST 136

__global__ __launch_bounds__(512, 1) void gru8(
    const unsigned short* __restrict__ GXR, const unsigned short* __restrict__ WB,
    const float* __restrict__ gbhh, float* __restrict__ HS) {
  __shared__ unsigned short Abuf[2][16 * AST];
  const int rec = blockIdx.y, bg = blockIdx.x;
  const int dir = rec & 1;
  const int t = threadIdx.x;
  const int w = t >> 6, lane = t & 63, q = lane >> 4, lm = lane & 15;
  const int o = w * 16 + lm;
  const int b = bg * 4 + q;

  short8 Bh[3][4];
  const unsigned short* whh = WB + WB_WHH + (size_t)rec * 49152;
#pragma unroll
  for (int gate = 0; gate < 3; ++gate)
#pragma unroll
    for (int c = 0; c < 4; ++c)
      Bh[gate][c] = *reinterpret_cast<const short8*>(
          whh + (size_t)(gate * 128 + o) * 128 + c * 32 + q * 8);
  const float bhn = gbhh[rec * 384 + 256 + o] * (2.f * LOG2E);
  const f32x4 czero = {0.f, 0.f, 0.f, 0.f};
  const f32x4 cbhn = {bhn, 0.f, 0.f, 0.f};

  float h = 0.f, hsum = 0.f;
  for (int i = t; i < 2 * 16 * AST; i += 512)
    (&Abuf[0][0])[i] = 0;

  // gx: 3 ushort loads/step from GXR[rec][b*512 + tt][384] at cols g*128+o.
  const unsigned short* gx0 = GXR + (size_t)rec * 12582912 +
      ((size_t)b * 512 + (dir ? 511 : 0)) * 384 + o;
  const ptrdiff_t st = dir ? -384 : 384;

  unsigned short ring[4][3];
#pragma unroll
  for (int pp = 0; pp < 4; ++pp) {
    const unsigned short* gp = gx0 + (ptrdiff_t)pp * st;
#pragma unroll
    for (int j = 0; j < 3; ++j) ring[pp][j] = gp[j * 128];
  }
  const unsigned short* pf = gx0 + (ptrdiff_t)4 * st;  // prefetch ptr (s+4)
  __syncthreads();

#pragma unroll 4
  for (int s = 0; s < SS; ++s) {
    const int p = s & 1, slot = s & 3;
    const float gxr = b2f(ring[slot][0]);
    const float gxz = b2f(ring[slot][1]);
    const float gxn = b2f(ring[slot][2]);
#pragma unroll
    for (int j = 0; j < 3; ++j) ring[slot][j] = pf[j * 128];
    pf += (s < SS - 5) ? st : 0;  // uniform-cond pointer bump, stays in-bounds

    short8 ah0 = *reinterpret_cast<const short8*>(&Abuf[p][lm * AST + 0 + q * 8]);
    short8 ah1 = *reinterpret_cast<const short8*>(&Abuf[p][lm * AST + 32 + q * 8]);
    short8 ah2 = *reinterpret_cast<const short8*>(&Abuf[p][lm * AST + 64 + q * 8]);
    short8 ah3 = *reinterpret_cast<const short8*>(&Abuf[p][lm * AST + 96 + q * 8]);
    f32x4 r0 = __builtin_amdgcn_mfma_f32_16x16x32_bf16(ah0, Bh[0][0], czero, 0, 0, 0);
    f32x4 r1 = __builtin_amdgcn_mfma_f32_16x16x32_bf16(ah2, Bh[0][2], czero, 0, 0, 0);
    f32x4 z0 = __builtin_amdgcn_mfma_f32_16x16x32_bf16(ah0, Bh[1][0], czero, 0, 0, 0);
    f32x4 z1 = __builtin_amdgcn_mfma_f32_16x16x32_bf16(ah2, Bh[1][2], czero, 0, 0, 0);
    f32x4 n0 = __builtin_amdgcn_mfma_f32_16x16x32_bf16(ah0, Bh[2][0], cbhn, 0, 0, 0);
    f32x4 n1 = __builtin_amdgcn_mfma_f32_16x16x32_bf16(ah2, Bh[2][2], czero, 0, 0, 0);
    r0 = __builtin_amdgcn_mfma_f32_16x16x32_bf16(ah1, Bh[0][1], r0, 0, 0, 0);
    r1 = __builtin_amdgcn_mfma_f32_16x16x32_bf16(ah3, Bh[0][3], r1, 0, 0, 0);
    z0 = __builtin_amdgcn_mfma_f32_16x16x32_bf16(ah1, Bh[1][1], z0, 0, 0, 0);
    z1 = __builtin_amdgcn_mfma_f32_16x16x32_bf16(ah3, Bh[1][3], z1, 0, 0, 0);
    n0 = __builtin_amdgcn_mfma_f32_16x16x32_bf16(ah1, Bh[2][1], n0, 0, 0, 0);
    n1 = __builtin_amdgcn_mfma_f32_16x16x32_bf16(ah3, Bh[2][3], n1, 0, 0, 0);

    float rr = frcp_(1.f + fexp2_(-(gxr + r0[0] + r1[0])));
    float zz = frcp_(1.f + fexp2_(-(gxz + z0[0] + z1[0])));
    float nn = 1.f - 2.f * frcp_(fexp2_(gxn + rr * (n0[0] + n1[0])) + 1.f);
    h = nn + zz * (h - nn);
    hsum += h;
    Abuf[p ^ 1][(q * 4) * AST + o] = f2b_trunc(h);
    asm volatile("s_waitcnt lgkmcnt(0)\n\ts_barrier" ::: "memory");
  }
  HS[((size_t)rec * BB + bg * 4 + q) * 128 + o] = hsum;
}

// ---------------------------------------------------------------------------
// Head: pooled -> Linear -> BN(eval) -> ReLU6 -> Linear.  grid=64, block=256.
// ---------------------------------------------------------------------------
__global__ __launch_bounds__(256) void head_kernel(
    const float* __restrict__ HS, const float* __restrict__ fW1,
    const float* __restrict__ fb1, const float* __restrict__ bng,
    const float* __restrict__ bnb, const float* __restrict__ fW2,
    const float* __restrict__ fb2, float* __restrict__ out) {
  __shared__ float pl[384];
  __shared__ float h1[256];
  int b = blockIdx.x, n = threadIdx.x;
  {
    int j = n;
    int seg = j >> 7, oo = j & 127;
    pl[j] = (HS[((size_t)seg * BB + b) * 128 + oo] +
             HS[((size_t)(seg + 3) * BB + b) * 128 + oo]) * (0.5f / 512.f);
  }
  if (n < 128) {
    int j = 256 + n;
    int seg = j >> 7, oo = j & 127;
    pl[j] = (HS[((size_t)seg * BB + b) * 128 + oo] +
             HS[((size_t)(seg + 3) * BB + b) * 128 + oo]) * (0.5f / 512.f);
  }
  __syncthreads();
  float acc = fb1[n];
  for (int k = 0; k < 384; ++k) acc += pl[k] * fW1[k * 256 + n];
  float hv = acc * rsqrtf(1.f + 1e-5f) * bng[n] + bnb[n];
  hv = fminf(fmaxf(hv, 0.f), 6.f);
  h1[n] = hv;
  __syncthreads();
  if (n < 8) {
    float a2 = fb2[n];
    for (int k = 0; k < 256; ++k) a2 += h1[k] * fW2[k * 8 + n];
    out[b * 8 + n] = a2;
  }
}

// ---------------------------------------------------------------------------
extern "C" void kernel_launch(void* const* d_in, const int* in_sizes, int n_in,
                              void* d_out, int out_size, void* d_ws,
                              size_t ws_size, hipStream_t stream) {
  (void)in_sizes; (void)n_in; (void)out_size; (void)ws_size;
  const float* text = (const float*)d_in[0];
  const float* vis  = (const float*)d_in[1];
  const float* aud  = (const float*)d_in[2];
  const float* fc1W = (const float*)d_in[3];
  const float* fc1b = (const float*)d_in[4];
  const float* fc2W = (const float*)d_in[5];
  const float* fc2b = (const float*)d_in[6];
  const float* fc3W = (const float*)d_in[7];
  const float* fc3b = (const float*)d_in[8];
  const float* Wq = (const float*)d_in[9];
  const float* bq = (const float*)d_in[10];
  const float* Wk = (const float*)d_in[11];
  const float* bk = (const float*)d_in[12];
  const float* Wv = (const float*)d_in[13];
  const float* bv = (const float*)d_in[14];
  const float* Wd = (const float*)d_in[15];
  const float* bd = (const float*)d_in[16];
  const float* lng = (const float*)d_in[17];
  const float* lnb = (const float*)d_in[18];
  const float* gWih = (const float*)d_in[19];
  const float* gWhh = (const float*)d_in[20];
  const float* gbih = (const float*)d_in[21];
  const float* gbhh = (const float*)d_in[22];
  const float* fW1 = (const float*)d_in[23];
  const float* fb1 = (const float*)d_in[24];
  const float* bng = (const float*)d_in[25];
  const float* bnb = (const float*)d_in[26];
  const float* fW2 = (const float*)d_in[27];
  const float* fb2 = (const float*)d_in[28];
  float* out = (float*)d_out;

  unsigned short* WSB = (unsigned short*)d_ws;
  unsigned short* T   = WSB;
  unsigned short* Vv  = WSB + SZ;
  unsigned short* Aa  = WSB + 2 * SZ;
  unsigned short* QKV = WSB + 3 * SZ;
  unsigned short* CTX = WSB + 12 * SZ;
  unsigned short* DOUT = WSB;
  unsigned short* GXR = WSB;              // slices 0..17 ([6][32768][384])
  unsigned short* GRUIN = WSB + 18 * SZ;  // slices 18..20
  unsigned short* WB  = WSB + 21 * SZ;
  float* VS = (float*)(WSB + 21 * SZ + 1048576);
  float* HS = VS + 6 * 64 * 128;
  float* gbihs = HS + 6 * 64 * 128;       // 2304 floats
  float* bqs = gbihs + 6 * 384;           // 768 floats

  prep_kernel<<<dim3(1024), dim3(256), 0, stream>>>(
      fc1W, fc2W, fc3W, Wq, Wk, Wv, Wd, gWih, gWhh, gbih, gbhh, bq, WB,
      gbihs, bqs);
  hipMemsetAsync(VS, 0, 6 * 64 * 128 * sizeof(float), stream);

  {
    GArgs ga{};
    ga.g[0] = {text, WB + WB_P1, fc1b, T, 300, 320, 0, 1, 128};
    ga.g[1] = {vis,  WB + WB_P2, fc2b, Vv, 35, 64, 0, 1, 128};
    ga.g[2] = {aud,  WB + WB_P3, fc3b, Aa, 74, 96, 0, 1, 128};
    gemm_b<<<dim3(256, 1, 3), dim3(256), 0, stream>>>(ga);
  }

  const int qsel[6] = {0, 2, 0, 1, 1, 2};
  const int ksel[6] = {2, 0, 1, 0, 2, 1};
  unsigned short* proj[3] = {T, Vv, Aa};

  for (int phase = 0; phase < 2; ++phase) {
    GArgs ga{};
    for (int ul = 0; ul < 3; ++ul) {
      int u = phase * 3 + ul;
      for (int op = 0; op < 3; ++op) {
        int z = ul * 3 + op;
        const float* bias = (op == 0) ? (bqs + u * 128)
                          : (op == 1) ? (bk + u * 128) : (bv + u * 128);
        float* vsum = (op == 2) ? (VS + (size_t)(phase * 3 + ul) * BB * DD)
                                : nullptr;
        ga.g[z] = {proj[op == 0 ? qsel[u] : ksel[u]],
                   WB + WB_QKVD + op * 98304 + u * 16384, bias,
                   QKV + (size_t)z * SZ, 128, 128, 1, 1, 128, vsum};
      }
    }
    gemm_b<<<dim3(256, 1, 9), dim3(256), 0, stream>>>(ga);
    attn2<<<dim3(2, 128, 3), dim3(256), 0, stream>>>(
        QKV, VS + phase * 3 * BB * DD, CTX + (size_t)phase * 3 * SZ);
  }

  {
    GArgs ga{};
    for (int u = 0; u < 6; ++u)
      ga.g[u] = {CTX + (size_t)u * SZ, WB + WB_QKVD + 3 * 98304 + u * 16384,
                 bd + u * 128, DOUT + (size_t)u * SZ, 128, 128, 1, 1, 128};
    gemm_b<<<dim3(256, 1, 6), dim3(256), 0, stream>>>(ga);
  }

  ln_pair<<<dim3(NROW / 4, 3), dim3(256), 0, stream>>>(DOUT, lng, lnb, GRUIN);

  // gx = GRUIN[g] @ Wih[rec]^T + gbihs[rec] -> row-major GXR (coalesced)
  {
    GArgs ga{};
    for (int r6 = 0; r6 < 6; ++r6) {
      int g = r6 >> 1;
      ga.g[r6] = {GRUIN + (size_t)g * SZ, WB + WB_WIH + r6 * 49152,
                  gbihs + r6 * 384, GXR + (size_t)r6 * 12582912,
                  128, 128, 1, 1, 384};
    }
    gemm_b<<<dim3(256, 3, 6), dim3(256), 0, stream>>>(ga);
  }

  gru8<<<dim3(16, 6), dim3(512), 0, stream>>>(GXR, WB, gbhh, HS);
  head_kernel<<<dim3(BB), dim3(256), 0, stream>>>(HS, fW1, fb1, bng, bnb, fW2, fb2, out);
}